// Round 3
// baseline (1028.734 us; speedup 1.0000x reference)
//
#include <hip/hip_runtime.h>
#include <stdint.h>

// ============================================================================
// y[m][n] = sum_k x[m][k] * W[n][k],  W = (wp>0)-(wn>0) in {-1,0,1}
// M=16384, N=4096, K=4096. bf16 MFMA (16x16x32), fp32 out.
//
// R3: faithful port of the m201 256^2 8-phase schedule (verified 1563/1728 TF,
// MfmaUtil 62%). R1/R2 "new templates" both plateaued at ~39-41% MfmaUtil.
// Key structural deltas vs R2:
//   - BK=64 K-step, double-buffered by SET: staging during step T writes
//     set (T+1)&1 while reads hit set T&1 -> zero intra-step write/read
//     coupling (no ring-slot constraints at all).
//   - K-half phase split: 4 phases/step = (kc, m-half). Each phase reads
//     4 or 8 frags from ONE half-buffer pair, stages ONE half-tile
//     (2 gloads), then {sched_barrier; s_barrier; setprio(1); 16 MFMA;
//     setprio(0); barrier} — the m196-isolated fine interleave.
//   - Counted waits, FIFO-derived: vmcnt(4) at end of P2 and P4 completes
//     exactly the half-pair the next 2 phases read; outstanding oscillates
//     4<->8 loads, never drains to 0 (last step: vmcnt(0) at P2 only).
//   - Stage->read distance = 4 phases (~1000+ cyc) > HBM latency.
// Carried: 8 waves 2Mx4N (wave tile 128x64), conflict-free chunk-major LDS
// (0 bank conflicts measured) via pre-permuted global source + linear
// global_load_lds dest, XCD-bijective block swizzle, 128 KB dynamic LDS.
// Numerics: identical fragments + identical K order => bit-identical to R2.
// ============================================================================

#define M_DIM 16384
#define N_DIM 4096
#define K_DIM 4096

#define BM 256
#define BN 256
#define NT 64                  // K / 64 steps
#define HBUF_U16 8192          // half-buffer: 256 rows x 32 k x 2B = 16 KiB
#define LDS_BYTES 131072       // 8 half-buffers (2 sets x 2 kc x {A,B})

typedef unsigned short u16;
typedef __attribute__((ext_vector_type(8))) __bf16 bf16x8;
typedef __attribute__((ext_vector_type(4))) float f32x4;

__device__ __forceinline__ u16 f2bf(float f) {
    unsigned u = __float_as_uint(f);
    u += 0x7FFFu + ((u >> 16) & 1u);   // round-to-nearest-even
    return (u16)(u >> 16);
}

// ---- prologue: x fp32 -> bf16 ----
__global__ void cvt_x_kernel(const float4* __restrict__ x, uint2* __restrict__ xb, int n4) {
    int i = blockIdx.x * 256 + threadIdx.x;
    if (i >= n4) return;
    float4 v = x[i];
    uint2 r;
    r.x = (unsigned)f2bf(v.x) | ((unsigned)f2bf(v.y) << 16);
    r.y = (unsigned)f2bf(v.z) | ((unsigned)f2bf(v.w) << 16);
    xb[i] = r;
}

// ---- prologue: W = (wp>0) - (wn>0) as bf16 {-1,0,1} (exact) ----
__device__ __forceinline__ unsigned enc_w(float a, float b) {
    int s = (int)(a > 0.f) - (int)(b > 0.f);
    return s == 0 ? 0u : (s > 0 ? 0x3F80u : 0xBF80u);
}

__global__ void binarize_w_kernel(const float4* __restrict__ wp, const float4* __restrict__ wn,
                                  uint2* __restrict__ wb, int n4) {
    int i = blockIdx.x * 256 + threadIdx.x;
    if (i >= n4) return;
    float4 p = wp[i];
    float4 q = wn[i];
    uint2 r;
    r.x = enc_w(p.x, q.x) | (enc_w(p.y, q.y) << 16);
    r.y = enc_w(p.z, q.z) | (enc_w(p.w, q.w) << 16);
    wb[i] = r;
}

// ---- async global -> LDS, 16B per lane ----
__device__ __forceinline__ void gload16(const u16* g, u16* l) {
    __builtin_amdgcn_global_load_lds(
        (const __attribute__((address_space(1))) void*)g,
        (__attribute__((address_space(3))) void*)l,
        16, 0, 0);
}

__launch_bounds__(512, 2)
__global__ void gemm_bin_kernel(const u16* __restrict__ A,   // [M][K] bf16 bits
                                const u16* __restrict__ B,   // [N][K] bf16 bits
                                float* __restrict__ C) {     // [M][N] fp32
    extern __shared__ __align__(16) u16 lds[];

    const int t    = threadIdx.x;
    const int lane = t & 63;
    const int wid  = t >> 6;
    const int wrow = wid >> 2;        // 0..1 : wave row (M)
    const int wcol = wid & 3;         // 0..3 : wave col (N)
    const int l15  = lane & 15;
    const int quad = lane >> 4;

    // T1: XCD-aware bijective swizzle. nwg = 16*64 = 1024, 1024 % 8 == 0.
    const int orig = blockIdx.y * 16 + blockIdx.x;
    const int wgid = (orig & 7) * 128 + (orig >> 3);
    const int bm = (wgid >> 4) * BM;
    const int bn = (wgid & 15) * BN;

    // --- staging: pre-permuted global source; LINEAR LDS dest == chunk-major
    // half-buffer layout (u16): off(row,c) = (row>>4)*512 + c*128 + (row&15)*8
    // thread covers T = t (rows 0-127) and T = t+512 (rows 128-255):
    //   row = (T>>6)*16 + (T&15), c = (T>>4)&3, dest off = T*8
    const int srow = ((t >> 6) << 4) | (t & 15);   // 0..127
    const int skk  = ((t >> 4) & 3) * 8;           // k-octet * 8
    const u16* gA0 = A + (size_t)(bm + srow) * K_DIM + skk;
    const u16* gA1 = gA0 + (size_t)128 * K_DIM;
    const u16* gB0 = B + (size_t)(bn + srow) * K_DIM + skk;
    const u16* gB1 = gB0 + (size_t)128 * K_DIM;
    const int ldst = t * 8;

    // half-buffer base index: (set*4 + kc*2 + ab) * HBUF_U16
#define STAGE_A(S, KC, U) do {                                                 \
        u16* d_ = lds + ((S) * 4 + (KC) * 2 + 0) * HBUF_U16 + ldst;            \
        const u16* s_ = gA0 + (U) * 64 + (KC) * 32;                            \
        gload16(s_, d_); gload16(s_ + (size_t)128 * K_DIM, d_ + 4096);         \
    } while (0)
#define STAGE_B(S, KC, U) do {                                                 \
        u16* d_ = lds + ((S) * 4 + (KC) * 2 + 1) * HBUF_U16 + ldst;            \
        const u16* s_ = gB0 + (U) * 64 + (KC) * 32;                            \
        gload16(s_, d_); gload16(s_ + (size_t)128 * K_DIM, d_ + 4096);         \
    } while (0)

    // fragment read offsets: each frag is a lane-contiguous 1 KiB region
    const int aoffs = wrow * 4096 + quad * 128 + l15 * 8;  // + mi*512
    const int boffs = wcol * 2048 + quad * 128 + l15 * 8;  // + ni*512

    f32x4 acc[8][4];
#pragma unroll
    for (int i = 0; i < 8; ++i)
#pragma unroll
        for (int j = 0; j < 4; ++j) acc[i][j] = (f32x4){0.f, 0.f, 0.f, 0.f};

    // prologue: stage step0 (set0): A.kc0, B.kc0, A.kc1, B.kc1 (8 loads);
    // wait oldest 4 (kc0 pair) -> entry invariant: 4 outstanding (kc1 pair)
    STAGE_A(0, 0, 0); STAGE_B(0, 0, 0);
    STAGE_A(0, 1, 0); STAGE_B(0, 1, 0);
    asm volatile("s_waitcnt vmcnt(4)" ::: "memory");
    __builtin_amdgcn_s_barrier();

#define MFMA16(MB, AF, BF)                                                     \
    _Pragma("unroll")                                                          \
    for (int mi = 0; mi < 4; ++mi)                                             \
        _Pragma("unroll")                                                      \
        for (int ni = 0; ni < 4; ++ni)                                         \
            acc[(MB) + mi][ni] = __builtin_amdgcn_mfma_f32_16x16x32_bf16(      \
                (AF)[mi], (BF)[ni], acc[(MB) + mi][ni], 0, 0, 0)

#define STEP(S, T) do {                                                        \
        const u16* As0 = lds + ((S) * 4 + 0) * HBUF_U16;                       \
        const u16* Bs0 = lds + ((S) * 4 + 1) * HBUF_U16;                       \
        const u16* As1 = lds + ((S) * 4 + 2) * HBUF_U16;                       \
        const u16* Bs1 = lds + ((S) * 4 + 3) * HBUF_U16;                       \
        const bool st_ = (T) + 1 < NT;                                         \
        bf16x8 afL[4], afH[4], bfr[4];                                         \
        /* ---- P1: kc0, m-half0 ---- */                                       \
        _Pragma("unroll")                                                      \
        for (int i = 0; i < 4; ++i) {                                          \
            afL[i] = *(const bf16x8*)(As0 + aoffs + i * 512);                  \
            bfr[i] = *(const bf16x8*)(Bs0 + boffs + i * 512);                  \
        }                                                                      \
        if (st_) STAGE_A(1 - (S), 0, (T) + 1);                                 \
        __builtin_amdgcn_sched_barrier(0);                                     \
        __builtin_amdgcn_s_barrier();                                          \
        __builtin_amdgcn_s_setprio(1);                                         \
        MFMA16(0, afL, bfr);                                                   \
        __builtin_amdgcn_s_setprio(0);                                         \
        __builtin_amdgcn_s_barrier();                                          \
        /* ---- P2: kc0, m-half1 ---- */                                       \
        _Pragma("unroll")                                                      \
        for (int i = 0; i < 4; ++i)                                            \
            afH[i] = *(const bf16x8*)(As0 + aoffs + (4 + i) * 512);            \
        if (st_) STAGE_B(1 - (S), 0, (T) + 1);                                 \
        __builtin_amdgcn_sched_barrier(0);                                     \
        __builtin_amdgcn_s_barrier();                                          \
        __builtin_amdgcn_s_setprio(1);                                         \
        MFMA16(4, afH, bfr);                                                   \
        __builtin_amdgcn_s_setprio(0);                                         \
        if (st_) asm volatile("s_waitcnt vmcnt(4)" ::: "memory");              \
        else     asm volatile("s_waitcnt vmcnt(0)" ::: "memory");              \
        __builtin_amdgcn_s_barrier();                                          \
        /* ---- P3: kc1, m-half0 ---- */                                       \
        _Pragma("unroll")                                                      \
        for (int i = 0; i < 4; ++i) {                                          \
            afL[i] = *(const bf16x8*)(As1 + aoffs + i * 512);                  \
            bfr[i] = *(const bf16x8*)(Bs1 + boffs + i * 512);                  \
        }                                                                      \
        if (st_) STAGE_A(1 - (S), 1, (T) + 1);                                 \
        __builtin_amdgcn_sched_barrier(0);                                     \
        __builtin_amdgcn_s_barrier();                                          \
        __builtin_amdgcn_s_setprio(1);                                         \
        MFMA16(0, afL, bfr);                                                   \
        __builtin_amdgcn_s_setprio(0);                                         \
        __builtin_amdgcn_s_barrier();                                          \
        /* ---- P4: kc1, m-half1 ---- */                                       \
        _Pragma("unroll")                                                      \
        for (int i = 0; i < 4; ++i)                                            \
            afH[i] = *(const bf16x8*)(As1 + aoffs + (4 + i) * 512);            \
        if (st_) STAGE_B(1 - (S), 1, (T) + 1);                                 \
        __builtin_amdgcn_sched_barrier(0);                                     \
        __builtin_amdgcn_s_barrier();                                          \
        __builtin_amdgcn_s_setprio(1);                                         \
        MFMA16(4, afH, bfr);                                                   \
        __builtin_amdgcn_s_setprio(0);                                         \
        if (st_) asm volatile("s_waitcnt vmcnt(4)" ::: "memory");              \
        __builtin_amdgcn_s_barrier();                                          \
    } while (0)

    for (int tt = 0; tt < NT; tt += 2) {
        STEP(0, tt);
        STEP(1, tt + 1);
    }

    // epilogue: C/D layout col = lane&15, row = quad*4 + r  [m89-verified]
#pragma unroll
    for (int mi = 0; mi < 8; ++mi) {
        const int row0 = bm + wrow * 128 + mi * 16 + quad * 4;
#pragma unroll
        for (int ni = 0; ni < 4; ++ni) {
            const int col = bn + wcol * 64 + ni * 16 + l15;
#pragma unroll
            for (int r = 0; r < 4; ++r)
                C[(size_t)(row0 + r) * N_DIM + col] = acc[mi][ni][r];
        }
    }
#undef STEP
#undef MFMA16
#undef STAGE_A
#undef STAGE_B
}

extern "C" void kernel_launch(void* const* d_in, const int* in_sizes, int n_in,
                              void* d_out, int out_size, void* d_ws, size_t ws_size,
                              hipStream_t stream) {
    const float* x  = (const float*)d_in[0];   // [16384][4096]
    const float* wp = (const float*)d_in[1];   // [4096][4096]
    const float* wn = (const float*)d_in[2];
    float* out = (float*)d_out;                // [16384][4096]

    // workspace layout: [0, 128MB) x_bf16 ; [128MB, 160MB) w_bf16
    u16* xb = (u16*)d_ws;
    u16* wb = (u16*)((char*)d_ws + (size_t)M_DIM * K_DIM * sizeof(u16));

    const int nx4 = M_DIM * K_DIM / 4;   // 16,777,216 float4s
    cvt_x_kernel<<<nx4 / 256, 256, 0, stream>>>((const float4*)x, (uint2*)xb, nx4);

    const int nw4 = N_DIM * K_DIM / 4;   // 4,194,304 float4s
    binarize_w_kernel<<<nw4 / 256, 256, 0, stream>>>(
        (const float4*)wp, (const float4*)wn, (uint2*)wb, nw4);

    static int s_attr_done = 0;
    if (!s_attr_done) {
        hipFuncSetAttribute((const void*)gemm_bin_kernel,
                            hipFuncAttributeMaxDynamicSharedMemorySize, LDS_BYTES);
        s_attr_done = 1;
    }
    dim3 grid(N_DIM / BN, M_DIM / BM);   // (16, 64) -> 1024 blocks
    gemm_bin_kernel<<<grid, 512, LDS_BYTES, stream>>>(xb, wb, out);
}